// Round 7
// baseline (34.236 us; speedup 1.0000x reference)
//
#include <hip/hip_runtime.h>

// FRAP forward — round 7: semi-parallel early chain + 8-WG row split.
// R6 (27.9us): 4 WGs x 14 positions, wave0-solo early chain. Model says the
// solo chain (~2100 FMA/lane serial) is now the longest segment.
// R7: (a) heavy early layers P1 (8x256,K=14) and P2 (8x32,K=256) run on ALL
// 8 waves (+2 barriers); only the cheap tail P3/P5/P6/P7 (~42k MAC) stays
// wave0-solo. (b) grid 8 x 512: each WG owns ONE output row (7 positions);
// conv work per WG halves; P8/P11 i=wg,k=sl (division gone).
//
// Per-WG LDS (floats, sm[4096] = 16KB):
//   early: feat16 @0(128) dh1 @128(2048) dh2 @2176(256) dem @2432(32)
//          ch1 @2464(1024) ch2 @3488(256)   [all dead before P8]
//   conv:  big @0 (7x256 swizzled [sl][c])  mid @3744 (32x7 [o][sl])
//          dp @3968(32)  Hd @4000(14, [2][7])  h3 @0(56, after P12)
// Swizzle: (sl,c) at big[sl*256 + ((c>>2)^sl)*4 + (c&3)]  (sl<7).

#define DEV __device__ __forceinline__

// Intra-wave LDS producer->consumer fence (rule #18).
#define WAVE_SYNC() do { \
    asm volatile("s_waitcnt lgkmcnt(0)" ::: "memory"); \
    __builtin_amdgcn_sched_barrier(0); \
} while (0)

DEV float dot4a(float acc, float4 a, float4 b) {
    acc = fmaf(a.x, b.x, acc);
    acc = fmaf(a.y, b.y, acc);
    acc = fmaf(a.z, b.z, acc);
    acc = fmaf(a.w, b.w, acc);
    return acc;
}

// Coalesced cache-warm over waves 1..7 (448 threads), id = t-64.
DEV float warm_arr(const float* __restrict__ p, int n4, int id, float sink) {
    const float4* p4 = (const float4*)p;
    for (int i = id; i < n4; i += 448) {
        float4 v = p4[i];
        sink += v.x + v.y + v.z + v.w;
    }
    return sink;
}

// conv h2: big (swizzled [sl][256], sl<7) -> relu(W(32x256)@.) -> mid[ch*7+sl]
// 512 thr, 2-way K-split: kq=t&1 (K-half), u=t>>1: ch=u>>3, sl=u&7 (7 idle).
DEV void conv_h2_vec(const float* __restrict__ big, const float* __restrict__ w2g,
                     const float* __restrict__ b2g, float* __restrict__ mid, int t)
{
    int kq = t & 1;
    int u  = t >> 1;
    int ch = u >> 3, sl = u & 7;
    float a0 = 0.0f, a1 = 0.0f, a2 = 0.0f, a3 = 0.0f;
    if (sl < 7) {
        const float4* wp = (const float4*)(w2g + ch * 256) + kq * 32;
        const float* hrow = big + (sl << 8);
#pragma unroll 2
        for (int g = 0; g < 32; g += 4) {
            int gg = kq * 32 + g;
            float4 w0 = wp[g + 0], w1 = wp[g + 1], w2 = wp[g + 2], w3 = wp[g + 3];
            float4 h0 = *(const float4*)(hrow + (((gg + 0) ^ sl) << 2));
            float4 h1 = *(const float4*)(hrow + (((gg + 1) ^ sl) << 2));
            float4 h2 = *(const float4*)(hrow + (((gg + 2) ^ sl) << 2));
            float4 h3v = *(const float4*)(hrow + (((gg + 3) ^ sl) << 2));
            a0 = dot4a(a0, h0, w0);
            a1 = dot4a(a1, h1, w1);
            a2 = dot4a(a2, h2, w2);
            a3 = dot4a(a3, h3v, w3);
        }
    }
    float r = (a0 + a1) + (a2 + a3);
    r += __shfl_xor(r, 1);             // combine the two K-halves
    if (sl < 7 && kq == 0)
        mid[ch * 7 + sl] = fmaxf(r + b2g[ch], 0.0f);
}

__global__ __launch_bounds__(512, 1) void frap_kernel(
    const float* __restrict__ waiting, const float* __restrict__ phase,
    const float* __restrict__ wtime_mu, const float* __restrict__ wtime_sigma,
    const float* __restrict__ wtime_max,
    const float* __restrict__ i_pos, const float* __restrict__ j_pos,
    const float* __restrict__ d_w1, const float* __restrict__ d_b1,
    const float* __restrict__ d_w2, const float* __restrict__ d_b2,
    const float* __restrict__ d_w3, const float* __restrict__ d_b3,
    const float* __restrict__ c_w1, const float* __restrict__ c_b1,
    const float* __restrict__ c_w2, const float* __restrict__ c_b2,
    const float* __restrict__ c_w3, const float* __restrict__ c_b3,
    const float* __restrict__ dD_w1, const float* __restrict__ dD_b1,
    const float* __restrict__ dD_w2, const float* __restrict__ dD_b2,
    const float* __restrict__ dD_w3, const float* __restrict__ dD_b3,
    const float* __restrict__ cC_w1, const float* __restrict__ cC_b1,
    const float* __restrict__ cC_w2, const float* __restrict__ cC_b2,
    const float* __restrict__ cC_w3, const float* __restrict__ cC_b3,
    const float* __restrict__ cC_w4, const float* __restrict__ cC_b4,
    float* __restrict__ out)
{
    __shared__ __align__(16) float sm[4096];   // 16 KB
    const int t  = threadIdx.x;
    const int wg = blockIdx.x;                 // 0..7: output row h = wg
    const int ln = t & 63;

    float* feat16 = sm;        // 128 (8 rows x 16, cols 14/15 = 0)
    float* dh1  = sm + 128;    // 2048
    float* dh2  = sm + 2176;   // 256
    float* dem  = sm + 2432;   // 32
    float* ch1  = sm + 2464;   // 1024
    float* ch2  = sm + 3488;   // 256
    float* big  = sm;          // 1792 (swizzled [sl][256]; overlaps dead early)
    float* mid  = sm + 3744;   // 224  [o][sl]
    float* dp   = sm + 3968;   // 32
    float* Hd   = sm + 4000;   // 14   [2][7]
    float* h3   = sm;          // 56 (reuses big after P12)

    // ---- P0 (wave0) + warm (waves 1..7), concurrent ----
    if (t < 64) {
        for (int rep = 0; rep < 2; ++rep) {
            int idx = rep * 64 + ln;
            int l = idx >> 4, c = idx & 15;
            float v = 0.0f;
            if      (c == 0) v = i_pos[0];
            else if (c == 1) v = j_pos[0];
            else if (c == 2) v = wtime_mu[l];
            else if (c == 3) v = wtime_sigma[l];
            else if (c == 4) v = wtime_max[l];
            else if (c == 5) v = waiting[l];
            else if (c < 14) v = phase[c - 6];
            feat16[idx] = v;
        }
    } else {
        int id = t - 64;    // 0..447
        float snk = 0.0f;
        snk = warm_arr(d_w1,  896, id, snk);
        snk = warm_arr(d_b1,   64, id, snk);
        snk = warm_arr(d_w2, 2048, id, snk);
        snk = warm_arr(d_b2,    8, id, snk);
        snk = warm_arr(d_w3,   32, id, snk);
        snk = warm_arr(d_b3,    1, id, snk);
        snk = warm_arr(c_w1,  256, id, snk);
        snk = warm_arr(c_b1,   32, id, snk);
        snk = warm_arr(c_w2, 1024, id, snk);
        snk = warm_arr(c_b2,    8, id, snk);
        snk = warm_arr(c_w3,   32, id, snk);
        snk = warm_arr(c_b3,    1, id, snk);
        snk = warm_arr(dD_w1, 512, id, snk);
        snk = warm_arr(dD_b1,  64, id, snk);
        snk = warm_arr(dD_w2, 2048, id, snk);
        snk = warm_arr(dD_b2,   8, id, snk);
        snk = warm_arr(dD_w3,  16, id, snk);
        snk = warm_arr(cC_w1, 192, id, snk);
        snk = warm_arr(cC_b1,  64, id, snk);
        snk = warm_arr(cC_w2, 2048, id, snk);
        snk = warm_arr(cC_b2,   8, id, snk);
        snk = warm_arr(cC_w3,  64, id, snk);
        snk = warm_arr(cC_b3,   2, id, snk);
        snk = warm_arr(cC_w4,  14, id, snk);
        asm volatile("" :: "v"(snk));
    }
    __syncthreads();

    // ---- P1 (ALL waves): dh1[l*256+o] = relu(feat @ d_w1^T), K=14 ----
    for (int q = 0; q < 4; ++q) {
        int idx = t + q * 512;
        int l = idx >> 8, o = idx & 255;
        const float* w = d_w1 + o * 14;
        const float* f = feat16 + l * 16;
        float acc = d_b1[o];
#pragma unroll
        for (int c = 0; c < 14; ++c) acc = fmaf(f[c], w[c], acc);
        dh1[idx] = fmaxf(acc, 0.0f);
    }
    __syncthreads();

    // ---- P2 (ALL waves): dh2[l*32+o], K=256, 2-way K-split ----
    {
        int kq = t & 1;
        int u  = t >> 1;                 // 0..255
        int l = u >> 5, o = u & 31;
        const float4* w = (const float4*)(d_w2 + o * 256) + kq * 32;
        const float4* h = (const float4*)(dh1 + l * 256) + kq * 32;
        float acc = 0.0f;
#pragma unroll 4
        for (int g = 0; g < 32; ++g) acc = dot4a(acc, h[g], w[g]);
        acc += __shfl_xor(acc, 1);
        if (kq == 0) dh2[l * 32 + o] = fmaxf(acc + d_b2[o], 0.0f);
    }
    __syncthreads();

    // ---- P3..P7 (wave0 solo; ~42k MAC tail) ----
    if (t < 64) {
        // P3: dem (8x4), K=32.
        if (ln < 32) {
            int l = ln >> 2, o = ln & 3;
            const float4* w = (const float4*)(d_w3 + o * 32);
            const float4* h = (const float4*)(dh2 + l * 32);
            float acc = d_b3[o];
#pragma unroll
            for (int g = 0; g < 8; ++g) acc = dot4a(acc, h[g], w[g]);
            dem[ln] = acc;
        }
        WAVE_SYNC();

        // P5: ch1[p*128+o], K=8, PAIRS folded.
        for (int rep = 0; rep < 2; ++rep) {
            int o = rep * 64 + ln;
            const float4* w = (const float4*)(c_w1 + o * 8);
            float4 w0 = w[0], w1 = w[1];
            float bias = c_b1[o];
#pragma unroll
            for (int p = 0; p < 8; ++p) {
                int a0 = p & 3;
                int a1 = (p < 4) ? (4 + (p & 3)) : (4 + ((p & 3) ^ 1));
                float4 va = *(const float4*)(dem + a0 * 4);
                float4 vb = *(const float4*)(dem + a1 * 4);
                float acc = dot4a(dot4a(bias, va, w0), vb, w1);
                ch1[p * 128 + o] = fmaxf(acc, 0.0f);
            }
        }
        WAVE_SYNC();

        // P6: ch2[l*32+o], K=128. lane = (lh, o), 4 rows each.
        {
            int o = ln & 31, lh = ln >> 5;
            float acc0 = 0.0f, acc1 = 0.0f, acc2 = 0.0f, acc3 = 0.0f;
            const float4* w4p = (const float4*)(c_w2 + o * 128);
#pragma unroll 4
            for (int cb = 0; cb < 32; ++cb) {
                float4 w = w4p[cb];
                float4 h0 = *(const float4*)(ch1 + (lh * 4 + 0) * 128 + cb * 4);
                float4 h1 = *(const float4*)(ch1 + (lh * 4 + 1) * 128 + cb * 4);
                float4 h2 = *(const float4*)(ch1 + (lh * 4 + 2) * 128 + cb * 4);
                float4 h3v = *(const float4*)(ch1 + (lh * 4 + 3) * 128 + cb * 4);
                acc0 = dot4a(acc0, h0, w);
                acc1 = dot4a(acc1, h1, w);
                acc2 = dot4a(acc2, h2, w);
                acc3 = dot4a(acc3, h3v, w);
            }
            float b = c_b2[o];
            ch2[(lh * 4 + 0) * 32 + o] = fmaxf(acc0 + b, 0.0f);
            ch2[(lh * 4 + 1) * 32 + o] = fmaxf(acc1 + b, 0.0f);
            ch2[(lh * 4 + 2) * 32 + o] = fmaxf(acc2 + b, 0.0f);
            ch2[(lh * 4 + 3) * 32 + o] = fmaxf(acc3 + b, 0.0f);
        }
        WAVE_SYNC();

        // P7: dp (8x4), K=32.
        if (ln < 32) {
            int l = ln >> 2, o = ln & 3;
            const float4* w = (const float4*)(c_w3 + o * 32);
            const float4* h = (const float4*)(ch2 + l * 32);
            float acc = c_b3[o];
#pragma unroll
            for (int g = 0; g < 8; ++g) acc = dot4a(acc, h[g], w[g]);
            dp[ln] = acc;
        }
    }
    __syncthreads();   // dp ready

    // ============ conv section on sl 0..6 (global s = wg*7+sl) ============
    // P8: conv_D h1 (256 ch x 7 sl), K=8 from dp. i=wg, k=sl, j=sl+(sl>=wg).
    {
        const float4* dp4 = (const float4*)dp;
        int o = t & 255;
        const float4* wrow = (const float4*)(dD_w1 + o * 8);
        float4 w0 = wrow[0], w1 = wrow[1];
        float bias = dD_b1[o];
        float4 di = dp4[wg];
#pragma unroll
        for (int it = 0; it < 4; ++it) {
            int sl = (t >> 8) + it * 2;
            if (sl < 7) {
                int j = sl + (sl >= wg ? 1 : 0);
                float acc = dot4a(dot4a(bias, di, w0), dp4[j], w1);
                big[(sl << 8) + (((o >> 2) ^ sl) << 2) + (o & 3)] = fmaxf(acc, 0.0f);
            }
        }
    }
    __syncthreads();

    // P9: conv_D h2 (32 x 7), K=256
    conv_h2_vec(big, dD_w2, dD_b2, mid, t);
    __syncthreads();

    // P10: conv_D h3 -> Hd (2 x 7), K=32. 4-way K-split.
    if (t < 56) {
        int kq = t & 3, u = t >> 2;          // u 0..13
        int o = (u >= 7) ? 1 : 0;
        int s = u - o * 7;
        float acc = 0.0f;
#pragma unroll
        for (int cc = 0; cc < 8; ++cc) {
            int c = kq * 8 + cc;
            acc = fmaf(mid[c * 7 + s], dD_w3[o * 32 + c], acc);
        }
        acc += __shfl_xor(acc, 1);
        acc += __shfl_xor(acc, 2);
        if (kq == 0) Hd[o * 7 + s] = acc + dD_b3[o];
    }
    __syncthreads();

    // P11: conv_C h1 (256 x 7): H_c channel 2 is zero -> 2 taps.
    {
        int o = t & 255;
        float w0 = cC_w1[o * 3], w1 = cC_w1[o * 3 + 1];
        float bias = cC_b1[o];
#pragma unroll
        for (int it = 0; it < 4; ++it) {
            int sl = (t >> 8) + it * 2;
            if (sl < 7) {
                float acc = fmaf(Hd[7 + sl], w1, fmaf(Hd[sl], w0, bias));
                big[(sl << 8) + (((o >> 2) ^ sl) << 2) + (o & 3)] = fmaxf(acc, 0.0f);
            }
        }
    }
    __syncthreads();

    // P12: conv_C h2 (32 x 7), K=256
    conv_h2_vec(big, cC_w2, cC_b2, mid, t);
    __syncthreads();

    // P13: conv_C h3 (8 x 7), K=32, relu -> h3. 4-way K-split, 224 thr.
    if (t < 224) {
        int kq = t & 3, u = t >> 2;          // u 0..55
        int o = u & 7, s = u >> 3;           // s 0..6
        float acc = 0.0f;
#pragma unroll
        for (int cc = 0; cc < 8; ++cc) {
            int c = kq * 8 + cc;
            acc = fmaf(mid[c * 7 + s], cC_w3[o * 32 + c], acc);
        }
        acc += __shfl_xor(acc, 1);
        acc += __shfl_xor(acc, 2);
        if (kq == 0) h3[o * 7 + s] = fmaxf(acc + cC_b3[o], 0.0f);
    }
    __syncthreads();

    // P14: final (1,7) conv for this WG's single row h=wg.
    if (t < 64) {
        float p = 0.0f;
        if (ln < 56) {
            int c = ln / 7, w = ln % 7;
            p = cC_w4[c * 7 + w] * h3[c * 7 + w];
        }
#pragma unroll
        for (int off = 1; off < 64; off <<= 1) p += __shfl_xor(p, off);
        if (ln == 0) out[wg] = p + cC_b4[0];
    }
}

extern "C" void kernel_launch(void* const* d_in, const int* in_sizes, int n_in,
                              void* d_out, int out_size, void* d_ws, size_t ws_size,
                              hipStream_t stream) {
    (void)in_sizes; (void)n_in; (void)d_ws; (void)ws_size; (void)out_size;
    const float* a[33];
    for (int i = 0; i < 33; ++i) a[i] = (const float*)d_in[i];
    frap_kernel<<<dim3(8), dim3(512), 0, stream>>>(
        a[0], a[1], a[2], a[3], a[4], a[5], a[6],
        a[7], a[8], a[9], a[10], a[11], a[12],
        a[13], a[14], a[15], a[16], a[17], a[18],
        a[19], a[20], a[21], a[22], a[23], a[24],
        a[25], a[26], a[27], a[28], a[29], a[30], a[31], a[32],
        (float*)d_out);
}

// Round 8
// 26.347 us; speedup vs baseline: 1.2994x; 1.2994x over previous
//
#include <hip/hip_runtime.h>

// FRAP forward — round 8: R6 early structure + R7 conv split.
// R7 post-mortem: joining warm BEFORE P1/P2 serialized warm + lockstep
// phases (34us, worse than R6's 27.9). The win in R6 was OVERLAP: wave0's
// whole solo chain runs concurrently with waves1-7's weight warm, one join.
// R8 = R6's early section verbatim + R7's halved conv section (8 WGs, one
// output row each, i=wg so the s/7 division disappears).
//
// Per-WG LDS (floats, sm[4096] = 16KB):
//   early (dead after join): feat16 @0(128) dh1 @128(2048) dh2 @2176(256)
//     dem @2432(32) ch1 @2464(1024) ch2 @3488(256)
//   conv:  big @0 (7x256 swizzled [sl][c])  mid @3744 (32x7 [o][sl])
//          dp @3968(32)  Hd @4000(14, [2][7])  h3 @0(56, after P12)
// Swizzle: (sl,c) at big[sl*256 + ((c>>2)^sl)*4 + (c&3)]  (sl<7).

#define DEV __device__ __forceinline__

// Intra-wave LDS producer->consumer fence (rule #18).
#define WAVE_SYNC() do { \
    asm volatile("s_waitcnt lgkmcnt(0)" ::: "memory"); \
    __builtin_amdgcn_sched_barrier(0); \
} while (0)

DEV float dot4a(float acc, float4 a, float4 b) {
    acc = fmaf(a.x, b.x, acc);
    acc = fmaf(a.y, b.y, acc);
    acc = fmaf(a.z, b.z, acc);
    acc = fmaf(a.w, b.w, acc);
    return acc;
}

// Coalesced cache-warm over waves 1..7 (448 threads), id = t-64.
DEV float warm_arr(const float* __restrict__ p, int n4, int id, float sink) {
    const float4* p4 = (const float4*)p;
    for (int i = id; i < n4; i += 448) {
        float4 v = p4[i];
        sink += v.x + v.y + v.z + v.w;
    }
    return sink;
}

// conv h2: big (swizzled [sl][256], sl<7) -> relu(W(32x256)@.) -> mid[ch*7+sl]
// 512 thr, 2-way K-split: kq=t&1 (K-half), u=t>>1: ch=u>>3, sl=u&7 (7 idle).
DEV void conv_h2_vec(const float* __restrict__ big, const float* __restrict__ w2g,
                     const float* __restrict__ b2g, float* __restrict__ mid, int t)
{
    int kq = t & 1;
    int u  = t >> 1;
    int ch = u >> 3, sl = u & 7;
    float a0 = 0.0f, a1 = 0.0f, a2 = 0.0f, a3 = 0.0f;
    if (sl < 7) {
        const float4* wp = (const float4*)(w2g + ch * 256) + kq * 32;
        const float* hrow = big + (sl << 8);
#pragma unroll 2
        for (int g = 0; g < 32; g += 4) {
            int gg = kq * 32 + g;
            float4 w0 = wp[g + 0], w1 = wp[g + 1], w2 = wp[g + 2], w3 = wp[g + 3];
            float4 h0 = *(const float4*)(hrow + (((gg + 0) ^ sl) << 2));
            float4 h1 = *(const float4*)(hrow + (((gg + 1) ^ sl) << 2));
            float4 h2 = *(const float4*)(hrow + (((gg + 2) ^ sl) << 2));
            float4 h3v = *(const float4*)(hrow + (((gg + 3) ^ sl) << 2));
            a0 = dot4a(a0, h0, w0);
            a1 = dot4a(a1, h1, w1);
            a2 = dot4a(a2, h2, w2);
            a3 = dot4a(a3, h3v, w3);
        }
    }
    float r = (a0 + a1) + (a2 + a3);
    r += __shfl_xor(r, 1);             // combine the two K-halves
    if (sl < 7 && kq == 0)
        mid[ch * 7 + sl] = fmaxf(r + b2g[ch], 0.0f);
}

__global__ __launch_bounds__(512, 1) void frap_kernel(
    const float* __restrict__ waiting, const float* __restrict__ phase,
    const float* __restrict__ wtime_mu, const float* __restrict__ wtime_sigma,
    const float* __restrict__ wtime_max,
    const float* __restrict__ i_pos, const float* __restrict__ j_pos,
    const float* __restrict__ d_w1, const float* __restrict__ d_b1,
    const float* __restrict__ d_w2, const float* __restrict__ d_b2,
    const float* __restrict__ d_w3, const float* __restrict__ d_b3,
    const float* __restrict__ c_w1, const float* __restrict__ c_b1,
    const float* __restrict__ c_w2, const float* __restrict__ c_b2,
    const float* __restrict__ c_w3, const float* __restrict__ c_b3,
    const float* __restrict__ dD_w1, const float* __restrict__ dD_b1,
    const float* __restrict__ dD_w2, const float* __restrict__ dD_b2,
    const float* __restrict__ dD_w3, const float* __restrict__ dD_b3,
    const float* __restrict__ cC_w1, const float* __restrict__ cC_b1,
    const float* __restrict__ cC_w2, const float* __restrict__ cC_b2,
    const float* __restrict__ cC_w3, const float* __restrict__ cC_b3,
    const float* __restrict__ cC_w4, const float* __restrict__ cC_b4,
    float* __restrict__ out)
{
    __shared__ __align__(16) float sm[4096];   // 16 KB
    const int t  = threadIdx.x;
    const int wg = blockIdx.x;                 // 0..7: output row h = wg
    const int ln = t & 63;

    float* feat16 = sm;        // 128 (8 rows x 16, cols 14/15 = 0)
    float* dh1  = sm + 128;    // 2048
    float* dh2  = sm + 2176;   // 256
    float* dem  = sm + 2432;   // 32
    float* ch1  = sm + 2464;   // 1024
    float* ch2  = sm + 3488;   // 256
    float* big  = sm;          // 1792 (swizzled [sl][256]; overlaps dead early)
    float* mid  = sm + 3744;   // 224  [o][sl]
    float* dp   = sm + 3968;   // 32
    float* Hd   = sm + 4000;   // 14   [2][7]
    float* h3   = sm;          // 56 (reuses big after P12)

    if (t < 64) {
        // ========== wave-solo early chain (identical in every WG) ==========
        // P0: feat16
        for (int rep = 0; rep < 2; ++rep) {
            int idx = rep * 64 + ln;
            int l = idx >> 4, c = idx & 15;
            float v = 0.0f;
            if      (c == 0) v = i_pos[0];
            else if (c == 1) v = j_pos[0];
            else if (c == 2) v = wtime_mu[l];
            else if (c == 3) v = wtime_sigma[l];
            else if (c == 4) v = wtime_max[l];
            else if (c == 5) v = waiting[l];
            else if (c < 14) v = phase[c - 6];
            feat16[idx] = v;
        }
        WAVE_SYNC();

        // P1: dh1[l*256+o] = relu(feat @ d_w1^T), K=14.
        for (int q = 0; q < 4; ++q) {
            int o = q * 64 + ln;
            const float* w = d_w1 + o * 14;
            float w0 = w[0], w1 = w[1], w2 = w[2], w3 = w[3], w4 = w[4];
            float w5 = w[5], w6 = w[6], w7 = w[7], w8 = w[8], w9 = w[9];
            float wa = w[10], wb = w[11], wc = w[12], wd = w[13];
            float bias = d_b1[o];
#pragma unroll
            for (int l = 0; l < 8; ++l) {
                const float4* f4 = (const float4*)(feat16 + l * 16);
                float4 f0 = f4[0], f1 = f4[1], f2 = f4[2], f3 = f4[3];
                float acc = bias;
                acc = fmaf(f0.x, w0, acc); acc = fmaf(f0.y, w1, acc);
                acc = fmaf(f0.z, w2, acc); acc = fmaf(f0.w, w3, acc);
                acc = fmaf(f1.x, w4, acc); acc = fmaf(f1.y, w5, acc);
                acc = fmaf(f1.z, w6, acc); acc = fmaf(f1.w, w7, acc);
                acc = fmaf(f2.x, w8, acc); acc = fmaf(f2.y, w9, acc);
                acc = fmaf(f2.z, wa, acc); acc = fmaf(f2.w, wb, acc);
                acc = fmaf(f3.x, wc, acc); acc = fmaf(f3.y, wd, acc);
                dh1[l * 256 + o] = fmaxf(acc, 0.0f);
            }
        }
        WAVE_SYNC();

        // P2: dh2[l*32+o], K=256. lane = (lh, o): 4 rows per lane.
        {
            int o = ln & 31, lh = ln >> 5;
            float acc0 = 0.0f, acc1 = 0.0f, acc2 = 0.0f, acc3 = 0.0f;
            const float4* w4p = (const float4*)(d_w2 + o * 256);
#pragma unroll 4
            for (int cb = 0; cb < 64; ++cb) {
                float4 w = w4p[cb];
                float4 h0 = *(const float4*)(dh1 + (lh * 4 + 0) * 256 + cb * 4);
                float4 h1 = *(const float4*)(dh1 + (lh * 4 + 1) * 256 + cb * 4);
                float4 h2 = *(const float4*)(dh1 + (lh * 4 + 2) * 256 + cb * 4);
                float4 h3v = *(const float4*)(dh1 + (lh * 4 + 3) * 256 + cb * 4);
                acc0 = dot4a(acc0, h0, w);
                acc1 = dot4a(acc1, h1, w);
                acc2 = dot4a(acc2, h2, w);
                acc3 = dot4a(acc3, h3v, w);
            }
            float b = d_b2[o];
            dh2[(lh * 4 + 0) * 32 + o] = fmaxf(acc0 + b, 0.0f);
            dh2[(lh * 4 + 1) * 32 + o] = fmaxf(acc1 + b, 0.0f);
            dh2[(lh * 4 + 2) * 32 + o] = fmaxf(acc2 + b, 0.0f);
            dh2[(lh * 4 + 3) * 32 + o] = fmaxf(acc3 + b, 0.0f);
        }
        WAVE_SYNC();

        // P3: dem (8x4), K=32.
        if (ln < 32) {
            int l = ln >> 2, o = ln & 3;
            const float4* w = (const float4*)(d_w3 + o * 32);
            const float4* h = (const float4*)(dh2 + l * 32);
            float acc = d_b3[o];
#pragma unroll
            for (int g = 0; g < 8; ++g) acc = dot4a(acc, h[g], w[g]);
            dem[ln] = acc;
        }
        WAVE_SYNC();

        // P5: ch1[p*128+o], K=8, PAIRS folded.
        for (int rep = 0; rep < 2; ++rep) {
            int o = rep * 64 + ln;
            const float4* w = (const float4*)(c_w1 + o * 8);
            float4 w0 = w[0], w1 = w[1];
            float bias = c_b1[o];
#pragma unroll
            for (int p = 0; p < 8; ++p) {
                int a0 = p & 3;
                int a1 = (p < 4) ? (4 + (p & 3)) : (4 + ((p & 3) ^ 1));
                float4 va = *(const float4*)(dem + a0 * 4);
                float4 vb = *(const float4*)(dem + a1 * 4);
                float acc = dot4a(dot4a(bias, va, w0), vb, w1);
                ch1[p * 128 + o] = fmaxf(acc, 0.0f);
            }
        }
        WAVE_SYNC();

        // P6: ch2[l*32+o], K=128.
        {
            int o = ln & 31, lh = ln >> 5;
            float acc0 = 0.0f, acc1 = 0.0f, acc2 = 0.0f, acc3 = 0.0f;
            const float4* w4p = (const float4*)(c_w2 + o * 128);
#pragma unroll 4
            for (int cb = 0; cb < 32; ++cb) {
                float4 w = w4p[cb];
                float4 h0 = *(const float4*)(ch1 + (lh * 4 + 0) * 128 + cb * 4);
                float4 h1 = *(const float4*)(ch1 + (lh * 4 + 1) * 128 + cb * 4);
                float4 h2 = *(const float4*)(ch1 + (lh * 4 + 2) * 128 + cb * 4);
                float4 h3v = *(const float4*)(ch1 + (lh * 4 + 3) * 128 + cb * 4);
                acc0 = dot4a(acc0, h0, w);
                acc1 = dot4a(acc1, h1, w);
                acc2 = dot4a(acc2, h2, w);
                acc3 = dot4a(acc3, h3v, w);
            }
            float b = c_b2[o];
            ch2[(lh * 4 + 0) * 32 + o] = fmaxf(acc0 + b, 0.0f);
            ch2[(lh * 4 + 1) * 32 + o] = fmaxf(acc1 + b, 0.0f);
            ch2[(lh * 4 + 2) * 32 + o] = fmaxf(acc2 + b, 0.0f);
            ch2[(lh * 4 + 3) * 32 + o] = fmaxf(acc3 + b, 0.0f);
        }
        WAVE_SYNC();

        // P7: dp (8x4), K=32.
        if (ln < 32) {
            int l = ln >> 2, o = ln & 3;
            const float4* w = (const float4*)(c_w3 + o * 32);
            const float4* h = (const float4*)(ch2 + l * 32);
            float acc = c_b3[o];
#pragma unroll
            for (int g = 0; g < 8; ++g) acc = dot4a(acc, h[g], w[g]);
            dp[ln] = acc;
        }
    } else {
        // ========== waves 1..7: warm full weight set into local XCD L2 ======
        int id = t - 64;    // 0..447
        float snk = 0.0f;
        snk = warm_arr(d_w1,  896, id, snk);
        snk = warm_arr(d_b1,   64, id, snk);
        snk = warm_arr(d_w2, 2048, id, snk);
        snk = warm_arr(d_b2,    8, id, snk);
        snk = warm_arr(d_w3,   32, id, snk);
        snk = warm_arr(d_b3,    1, id, snk);
        snk = warm_arr(c_w1,  256, id, snk);
        snk = warm_arr(c_b1,   32, id, snk);
        snk = warm_arr(c_w2, 1024, id, snk);
        snk = warm_arr(c_b2,    8, id, snk);
        snk = warm_arr(c_w3,   32, id, snk);
        snk = warm_arr(c_b3,    1, id, snk);
        snk = warm_arr(dD_w1, 512, id, snk);
        snk = warm_arr(dD_b1,  64, id, snk);
        snk = warm_arr(dD_w2, 2048, id, snk);
        snk = warm_arr(dD_b2,   8, id, snk);
        snk = warm_arr(dD_w3,  16, id, snk);
        snk = warm_arr(cC_w1, 192, id, snk);
        snk = warm_arr(cC_b1,  64, id, snk);
        snk = warm_arr(cC_w2, 2048, id, snk);
        snk = warm_arr(cC_b2,   8, id, snk);
        snk = warm_arr(cC_w3,  64, id, snk);
        snk = warm_arr(cC_b3,   2, id, snk);
        snk = warm_arr(cC_w4,  14, id, snk);
        asm volatile("" :: "v"(snk));
    }
    __syncthreads();   // single join: dp ready, weights warm

    // ============ conv section on sl 0..6 (global s = wg*7+sl) ============
    // P8: conv_D h1 (256 ch x 7 sl), K=8 from dp. i=wg, k=sl, j=sl+(sl>=wg).
    {
        const float4* dp4 = (const float4*)dp;
        int o = t & 255;
        const float4* wrow = (const float4*)(dD_w1 + o * 8);
        float4 w0 = wrow[0], w1 = wrow[1];
        float bias = dD_b1[o];
        float4 di = dp4[wg];
#pragma unroll
        for (int it = 0; it < 4; ++it) {
            int sl = (t >> 8) + it * 2;
            if (sl < 7) {
                int j = sl + (sl >= wg ? 1 : 0);
                float acc = dot4a(dot4a(bias, di, w0), dp4[j], w1);
                big[(sl << 8) + (((o >> 2) ^ sl) << 2) + (o & 3)] = fmaxf(acc, 0.0f);
            }
        }
    }
    __syncthreads();

    // P9: conv_D h2 (32 x 7), K=256
    conv_h2_vec(big, dD_w2, dD_b2, mid, t);
    __syncthreads();

    // P10: conv_D h3 -> Hd (2 x 7), K=32. 4-way K-split.
    if (t < 56) {
        int kq = t & 3, u = t >> 2;          // u 0..13
        int o = (u >= 7) ? 1 : 0;
        int s = u - o * 7;
        float acc = 0.0f;
#pragma unroll
        for (int cc = 0; cc < 8; ++cc) {
            int c = kq * 8 + cc;
            acc = fmaf(mid[c * 7 + s], dD_w3[o * 32 + c], acc);
        }
        acc += __shfl_xor(acc, 1);
        acc += __shfl_xor(acc, 2);
        if (kq == 0) Hd[o * 7 + s] = acc + dD_b3[o];
    }
    __syncthreads();

    // P11: conv_C h1 (256 x 7): H_c channel 2 is zero -> 2 taps.
    {
        int o = t & 255;
        float w0 = cC_w1[o * 3], w1 = cC_w1[o * 3 + 1];
        float bias = cC_b1[o];
#pragma unroll
        for (int it = 0; it < 4; ++it) {
            int sl = (t >> 8) + it * 2;
            if (sl < 7) {
                float acc = fmaf(Hd[7 + sl], w1, fmaf(Hd[sl], w0, bias));
                big[(sl << 8) + (((o >> 2) ^ sl) << 2) + (o & 3)] = fmaxf(acc, 0.0f);
            }
        }
    }
    __syncthreads();

    // P12: conv_C h2 (32 x 7), K=256
    conv_h2_vec(big, cC_w2, cC_b2, mid, t);
    __syncthreads();

    // P13: conv_C h3 (8 x 7), K=32, relu -> h3. 4-way K-split, 224 thr.
    if (t < 224) {
        int kq = t & 3, u = t >> 2;          // u 0..55
        int o = u & 7, s = u >> 3;           // s 0..6
        float acc = 0.0f;
#pragma unroll
        for (int cc = 0; cc < 8; ++cc) {
            int c = kq * 8 + cc;
            acc = fmaf(mid[c * 7 + s], cC_w3[o * 32 + c], acc);
        }
        acc += __shfl_xor(acc, 1);
        acc += __shfl_xor(acc, 2);
        if (kq == 0) h3[o * 7 + s] = fmaxf(acc + cC_b3[o], 0.0f);
    }
    __syncthreads();

    // P14: final (1,7) conv for this WG's single row h=wg.
    if (t < 64) {
        float p = 0.0f;
        if (ln < 56) {
            int c = ln / 7, w = ln % 7;
            p = cC_w4[c * 7 + w] * h3[c * 7 + w];
        }
#pragma unroll
        for (int off = 1; off < 64; off <<= 1) p += __shfl_xor(p, off);
        if (ln == 0) out[wg] = p + cC_b4[0];
    }
}

extern "C" void kernel_launch(void* const* d_in, const int* in_sizes, int n_in,
                              void* d_out, int out_size, void* d_ws, size_t ws_size,
                              hipStream_t stream) {
    (void)in_sizes; (void)n_in; (void)d_ws; (void)ws_size; (void)out_size;
    const float* a[33];
    for (int i = 0; i < 33; ++i) a[i] = (const float*)d_in[i];
    frap_kernel<<<dim3(8), dim3(512), 0, stream>>>(
        a[0], a[1], a[2], a[3], a[4], a[5], a[6],
        a[7], a[8], a[9], a[10], a[11], a[12],
        a[13], a[14], a[15], a[16], a[17], a[18],
        a[19], a[20], a[21], a[22], a[23], a[24],
        a[25], a[26], a[27], a[28], a[29], a[30], a[31], a[32],
        (float*)d_out);
}